// Round 1
// baseline (6644.799 us; speedup 1.0000x reference)
//
#include <hip/hip_runtime.h>

#define DIMD 256
#define KCB  4096
#define NQ   4
#define NTOK 32768   // 8 * 4096
#define TM   64
#define TK   64
#define DKC  32

// ---------------------------------------------------------------- reductions
__device__ __forceinline__ float blockReduceSum256(float v, float* sbuf) {
  // 256 threads = 4 waves of 64
  #pragma unroll
  for (int off = 32; off > 0; off >>= 1) v += __shfl_down(v, off, 64);
  const int lane = threadIdx.x & 63;
  const int wid  = threadIdx.x >> 6;
  if (lane == 0) sbuf[wid] = v;
  __syncthreads();
  float r = 0.f;
  if (threadIdx.x == 0) r = sbuf[0] + sbuf[1] + sbuf[2] + sbuf[3];
  return r;  // valid on thread 0 only
}

// ------------------------------------------------------------------- kernels
__global__ void init_kernel(const float* __restrict__ x,
                            float* __restrict__ res,
                            float* __restrict__ rn) {
  __shared__ float sbuf[4];
  const int n = blockIdx.x;
  const int d = threadIdx.x;
  const float v = x[n * DIMD + d];
  res[n * DIMD + d] = v;
  const float s = blockReduceSum256(v * v, sbuf);
  if (threadIdx.x == 0) rn[n] = s;
}

__global__ void cn_kernel(const float* __restrict__ cb,
                          float* __restrict__ cn) {
  __shared__ float sbuf[4];
  const int c = blockIdx.x;
  const float v = cb[c * DIMD + threadIdx.x];
  const float s = blockReduceSum256(v * v, sbuf);
  if (threadIdx.x == 0) cn[c] = s;
}

// Fused distance-GEMM + per-row best-2 argmin candidates.
// Block: 256 threads = 16(tr) x 16(tc); tile 64 rows x 64 codes, 4x4/thread.
__global__ __launch_bounds__(256, 2) void argmin_kernel(
    const float* __restrict__ res,   // [NTOK][DIMD]
    const float* __restrict__ cb,    // [KCB][DIMD] (this layer)
    const float* __restrict__ cn,    // [KCB]
    const float* __restrict__ rn,    // [NTOK]
    int2* __restrict__ cand)         // [NTOK] best-2 candidate indices
{
  __shared__ float As[DIMD * TM];   // [d][r]  64 KB
  __shared__ float Bs[DKC * TK];    // [d][c]   8 KB
  __shared__ float rnS[TM];

  const int tid = threadIdx.x;
  const int rm  = blockIdx.x * TM;

  // Stage A (rows) transposed into LDS: coalesced float4 global reads.
  #pragma unroll
  for (int i = 0; i < 16; ++i) {
    const int g  = i * 256 + tid;   // float4 id over 64 rows x 64 float4s
    const int r  = g >> 6;
    const int d4 = g & 63;
    const float4 v = *reinterpret_cast<const float4*>(&res[(rm + r) * DIMD + d4 * 4]);
    As[(d4 * 4 + 0) * TM + r] = v.x;
    As[(d4 * 4 + 1) * TM + r] = v.y;
    As[(d4 * 4 + 2) * TM + r] = v.z;
    As[(d4 * 4 + 3) * TM + r] = v.w;
  }
  if (tid < TM) rnS[tid] = rn[rm + tid];

  const int tr = tid & 15, tc = tid >> 4;

  float b1v[4], b2v[4];
  int   b1i[4], b2i[4];
  #pragma unroll
  for (int ri = 0; ri < 4; ++ri) { b1v[ri] = 1e30f; b2v[ri] = 1e30f; b1i[ri] = 0; b2i[ri] = 1; }

  // Prefetch first B chunk (kc=0, dk=0) into registers.
  float4 pre0, pre1;
  {
    int g = tid, c = g >> 3, e = g & 7;
    pre0 = *reinterpret_cast<const float4*>(&cb[c * DIMD + e * 4]);
    g = 256 + tid; c = g >> 3; e = g & 7;
    pre1 = *reinterpret_cast<const float4*>(&cb[c * DIMD + e * 4]);
  }

  for (int kc = 0; kc < KCB / TK; ++kc) {
    float acc[4][4];
    #pragma unroll
    for (int ri = 0; ri < 4; ++ri)
      #pragma unroll
      for (int ci = 0; ci < 4; ++ci) acc[ri][ci] = 0.f;

    for (int dk = 0; dk < DIMD / DKC; ++dk) {
      __syncthreads();
      { // store prefetched chunk (kc,dk) into Bs, transposed
        int g = tid, c = g >> 3, e = g & 7;
        float* bp = &Bs[(e * 4) * TK + c];
        bp[0 * TK] = pre0.x; bp[1 * TK] = pre0.y; bp[2 * TK] = pre0.z; bp[3 * TK] = pre0.w;
        g = 256 + tid; c = g >> 3; e = g & 7;
        bp = &Bs[(e * 4) * TK + c];
        bp[0 * TK] = pre1.x; bp[1 * TK] = pre1.y; bp[2 * TK] = pre1.z; bp[3 * TK] = pre1.w;
      }
      __syncthreads();
      { // prefetch next chunk
        int ndk = dk + 1, nkc = kc;
        if (ndk == DIMD / DKC) { ndk = 0; ++nkc; }
        if (nkc < KCB / TK) {
          int g = tid, c = g >> 3, e = g & 7;
          pre0 = *reinterpret_cast<const float4*>(&cb[(nkc * TK + c) * DIMD + ndk * DKC + e * 4]);
          g = 256 + tid; c = g >> 3; e = g & 7;
          pre1 = *reinterpret_cast<const float4*>(&cb[(nkc * TK + c) * DIMD + ndk * DKC + e * 4]);
        }
      }
      #pragma unroll
      for (int dd = 0; dd < DKC; ++dd) {
        const float4 a = *reinterpret_cast<const float4*>(&As[(dk * DKC + dd) * TM + 4 * tr]);
        const float4 b = *reinterpret_cast<const float4*>(&Bs[dd * TK + 4 * tc]);
        acc[0][0] = fmaf(a.x, b.x, acc[0][0]);
        acc[0][1] = fmaf(a.x, b.y, acc[0][1]);
        acc[0][2] = fmaf(a.x, b.z, acc[0][2]);
        acc[0][3] = fmaf(a.x, b.w, acc[0][3]);
        acc[1][0] = fmaf(a.y, b.x, acc[1][0]);
        acc[1][1] = fmaf(a.y, b.y, acc[1][1]);
        acc[1][2] = fmaf(a.y, b.z, acc[1][2]);
        acc[1][3] = fmaf(a.y, b.w, acc[1][3]);
        acc[2][0] = fmaf(a.z, b.x, acc[2][0]);
        acc[2][1] = fmaf(a.z, b.y, acc[2][1]);
        acc[2][2] = fmaf(a.z, b.z, acc[2][2]);
        acc[2][3] = fmaf(a.z, b.w, acc[2][3]);
        acc[3][0] = fmaf(a.w, b.x, acc[3][0]);
        acc[3][1] = fmaf(a.w, b.y, acc[3][1]);
        acc[3][2] = fmaf(a.w, b.z, acc[3][2]);
        acc[3][3] = fmaf(a.w, b.w, acc[3][3]);
      }
    }
    // epilogue: distances + best-2 tracking (ref order: (rn - 2*dot) + cn)
    const float4 cn4 = *reinterpret_cast<const float4*>(&cn[kc * TK + 4 * tc]);
    const float cnv[4] = {cn4.x, cn4.y, cn4.z, cn4.w};
    #pragma unroll
    for (int ri = 0; ri < 4; ++ri) {
      const float rnr = rnS[4 * tr + ri];
      #pragma unroll
      for (int ci = 0; ci < 4; ++ci) {
        const float dist = (rnr - 2.0f * acc[ri][ci]) + cnv[ci];
        const int cidx = kc * TK + 4 * tc + ci;
        if (dist < b1v[ri]) {
          b2v[ri] = b1v[ri]; b2i[ri] = b1i[ri];
          b1v[ri] = dist;    b1i[ri] = cidx;
        } else if (dist < b2v[ri]) {
          b2v[ri] = dist; b2i[ri] = cidx;
        }
      }
    }
  }

  // cross-thread (tc) reduction; reuse As as scratch (done with tiles)
  __syncthreads();
  float* sv1 = As;
  int*   si1 = (int*)(As + 1024);
  float* sv2 = As + 2048;
  int*   si2 = (int*)(As + 3072);
  #pragma unroll
  for (int ri = 0; ri < 4; ++ri) {
    const int r = 4 * tr + ri;
    sv1[r * 16 + tc] = b1v[ri]; si1[r * 16 + tc] = b1i[ri];
    sv2[r * 16 + tc] = b2v[ri]; si2[r * 16 + tc] = b2i[ri];
  }
  __syncthreads();
  if (tid < TM) {
    const int r = tid;
    float v1 = 1e30f, v2 = 1e30f; int i1 = 0, i2 = 1;
    for (int j = 0; j < 16; ++j) {
      float av = sv1[r * 16 + j]; int ai = si1[r * 16 + j];
      if (av < v1 || (av == v1 && ai < i1)) { v2 = v1; i2 = i1; v1 = av; i1 = ai; }
      else if (av < v2 || (av == v2 && ai < i2)) { v2 = av; i2 = ai; }
      av = sv2[r * 16 + j]; ai = si2[r * 16 + j];
      if (av < v1 || (av == v1 && ai < i1)) { v2 = v1; i2 = i1; v1 = av; i1 = ai; }
      else if (av < v2 || (av == v2 && ai < i2)) { v2 = av; i2 = ai; }
    }
    cand[rm + r] = make_int2(i1, i2);
  }
}

// Exact fp64 rescore of the 2 candidates -> final index (fp64-true argmin).
__global__ void rescore_kernel(const float* __restrict__ res,
                               const float* __restrict__ cb,
                               const int2* __restrict__ cand,
                               int* __restrict__ idx,
                               float* __restrict__ idxf) {
  const int lane = threadIdx.x & 63;
  const int rsub = threadIdx.x >> 6;
  const int n = blockIdx.x * 4 + rsub;
  const int2 c = cand[n];
  const float* rrow = res + (size_t)n * DIMD;
  const float* c1 = cb + (size_t)c.x * DIMD;
  const float* c2 = cb + (size_t)c.y * DIMD;
  double d1 = 0.0, d2 = 0.0;
  #pragma unroll
  for (int j = 0; j < 4; ++j) {
    const int d = j * 64 + lane;
    const double rv = (double)rrow[d];
    const double t1 = rv - (double)c1[d];
    const double t2 = rv - (double)c2[d];
    d1 += t1 * t1; d2 += t2 * t2;
  }
  #pragma unroll
  for (int off = 32; off > 0; off >>= 1) {
    d1 += __shfl_down(d1, off, 64);
    d2 += __shfl_down(d2, off, 64);
  }
  if (lane == 0) {
    const int best = (d2 < d1 || (d2 == d1 && c.y < c.x)) ? c.y : c.x;
    idx[n]  = best;
    idxf[n] = (float)best;
  }
}

// Residual/STE update + next-layer row norms + commit loss.
__global__ void update_kernel(float* __restrict__ res,
                              const float* __restrict__ cb,
                              const int* __restrict__ idx,
                              float* __restrict__ out,
                              float* __restrict__ rn,
                              float* __restrict__ loss) {
  __shared__ float sbuf[4];
  __shared__ float sbuf2[4];
  const int n = blockIdx.x;
  const int d = threadIdx.x;
  const int i = idx[n];
  const float r = res[n * DIMD + d];
  const float q = cb[(size_t)i * DIMD + d];
  const float qq = r + (q - r);   // STE value, same rounding as reference
  const float nr = r - qq;        // new residual
  const float dl = r - q;         // loss term uses raw q
  res[n * DIMD + d] = nr;
  out[n * DIMD + d] += qq;
  float s1 = nr * nr, s2 = dl * dl;
  #pragma unroll
  for (int off = 32; off > 0; off >>= 1) {
    s1 += __shfl_down(s1, off, 64);
    s2 += __shfl_down(s2, off, 64);
  }
  const int lane = threadIdx.x & 63, wid = threadIdx.x >> 6;
  if (lane == 0) { sbuf[wid] = s1; sbuf2[wid] = s2; }
  __syncthreads();
  if (threadIdx.x == 0) {
    const float t1 = sbuf[0] + sbuf[1] + sbuf[2] + sbuf[3];
    const float t2 = sbuf2[0] + sbuf2[1] + sbuf2[2] + sbuf2[3];
    rn[n] = t1;
    atomicAdd(loss, t2 * (1.0f / (float)((size_t)NTOK * DIMD)));
  }
}

// ------------------------------------------------------------------- launch
extern "C" void kernel_launch(void* const* d_in, const int* in_sizes, int n_in,
                              void* d_out, int out_size, void* d_ws, size_t ws_size,
                              hipStream_t stream) {
  const float* x   = (const float*)d_in[0];   // [8,4096,256]
  const float* cbs = (const float*)d_in[1];   // [4,4096,256]

  float* out    = (float*)d_out;                       // [NTOK*DIMD]
  float* idxf   = out + (size_t)NTOK * DIMD;           // [NQ*NTOK] as float
  float* losses = idxf + (size_t)NQ * NTOK;            // [NQ]

  char* w = (char*)d_ws;
  float* res  = (float*)w;  w += (size_t)NTOK * DIMD * sizeof(float);
  float* rn   = (float*)w;  w += (size_t)NTOK * sizeof(float);
  float* cn   = (float*)w;  w += (size_t)NQ * KCB * sizeof(float);
  int*   idx  = (int*)w;    w += (size_t)NTOK * sizeof(int);
  int2*  cand = (int2*)w;   w += (size_t)NTOK * sizeof(int2);

  hipMemsetAsync(d_out, 0, (size_t)out_size * sizeof(float), stream);
  init_kernel<<<NTOK, 256, 0, stream>>>(x, res, rn);
  cn_kernel<<<NQ * KCB, 256, 0, stream>>>(cbs, cn);

  for (int q = 0; q < NQ; ++q) {
    const float* cb = cbs + (size_t)q * KCB * DIMD;
    argmin_kernel<<<NTOK / TM, 256, 0, stream>>>(res, cb, cn + (size_t)q * KCB, rn, cand);
    rescore_kernel<<<NTOK / 4, 256, 0, stream>>>(res, cb, cand, idx, idxf + (size_t)q * NTOK);
    update_kernel<<<NTOK, 256, 0, stream>>>(res, cb, idx, out, rn, losses + q);
  }
}

// Round 2
// 3564.358 us; speedup vs baseline: 1.8642x; 1.8642x over previous
//
#include <hip/hip_runtime.h>
#include <cstdint>

#define DIMD 256
#define KCB  4096
#define NQ   4
#define NTOK 32768   // 8 * 4096
#define BM   128
#define BN   128
#define BK   32

typedef __attribute__((ext_vector_type(8))) short short8;
typedef __attribute__((ext_vector_type(8))) unsigned short ushort8;
typedef __attribute__((ext_vector_type(4))) float f32x4;

// ---------------------------------------------------------------- helpers
__device__ __forceinline__ unsigned short f2bf(float f) {
  uint32_t u = __float_as_uint(f);
  uint32_t r = (u + 0x7FFFu + ((u >> 16) & 1u)) >> 16;  // RNE
  return (unsigned short)r;
}
__device__ __forceinline__ float bf2f(unsigned short h) {
  return __uint_as_float(((uint32_t)h) << 16);
}

__device__ __forceinline__ void async16(const void* g, void* l) {
  __builtin_amdgcn_global_load_lds(
      (const __attribute__((address_space(1))) unsigned int*)g,
      (__attribute__((address_space(3))) unsigned int*)l, 16, 0, 0);
}

__device__ __forceinline__ f32x4 mfma16(short8 a, short8 b, f32x4 c) {
  return __builtin_amdgcn_mfma_f32_16x16x32_bf16(a, b, c, 0, 0, 0);
}

// merge candidate pair (u1,j1),(u2,j2) with u1<=u2 into best2 (v1,i1,v2,i2)
__device__ __forceinline__ void merge2(float& v1, int& i1, float& v2, int& i2,
                                       float u1, int j1, float u2, int j2) {
  if (u1 < v1 || (u1 == v1 && j1 < i1)) {
    v2 = v1; i2 = i1; v1 = u1; i1 = j1;
  } else if (u1 < v2 || (u1 == v2 && j1 < i2)) {
    v2 = u1; i2 = j1;
  }
  if (u2 < v2 || (u2 == v2 && j2 < i2)) {
    if (u2 < v1 || (u2 == v1 && j2 < i1)) { v2 = v1; i2 = i1; v1 = u2; i1 = j2; }
    else { v2 = u2; i2 = j2; }
  }
}
__device__ __forceinline__ void merge1(float& v1, int& i1, float& v2, int& i2,
                                       float u, int j) {
  if (u < v1 || (u == v1 && j < i1)) { v2 = v1; i2 = i1; v1 = u; i1 = j; }
  else if (u < v2 || (u == v2 && j < i2)) { v2 = u; i2 = j; }
}

// ---------------------------------------------------------------- prep kernels
// Pre-tiled swizzled plane layout: element (row R, d) with kc=d>>5, q=(d>>3)&3,
// j=d&7 stored at slot = (kc*NROWS + R)*4 + (q ^ ((R>>1)&3)), 8 ushorts per slot.

__global__ void init_kernel(const float* __restrict__ x,
                            float* __restrict__ res,
                            unsigned short* __restrict__ Ah,
                            unsigned short* __restrict__ Al) {
  const int tid = threadIdx.x;
  const int n = blockIdx.x * 8 + (tid >> 5);
  const int t = tid & 31;
  const float4 v0 = *(const float4*)&x[(size_t)n * DIMD + t * 8];
  const float4 v1 = *(const float4*)&x[(size_t)n * DIMD + t * 8 + 4];
  *(float4*)&res[(size_t)n * DIMD + t * 8]     = v0;
  *(float4*)&res[(size_t)n * DIMD + t * 8 + 4] = v1;
  const float f[8] = {v0.x, v0.y, v0.z, v0.w, v1.x, v1.y, v1.z, v1.w};
  ushort8 h, l;
  #pragma unroll
  for (int j = 0; j < 8; ++j) {
    const unsigned short hb = f2bf(f[j]);
    h[j] = hb;
    l[j] = f2bf(f[j] - bf2f(hb));
  }
  const int kc = t >> 2, qd = t & 3;
  const size_t slot = ((size_t)(kc * NTOK + n)) * 4 + (qd ^ ((n >> 1) & 3));
  *(ushort8*)&Ah[slot * 8] = h;
  *(ushort8*)&Al[slot * 8] = l;
}

__global__ void cb_prep_kernel(const float* __restrict__ cbs,
                               unsigned short* __restrict__ Bh,
                               unsigned short* __restrict__ Bl,
                               float* __restrict__ cn) {
  const int tid = threadIdx.x;
  const int R = blockIdx.x * 8 + (tid >> 5);   // 0..16383 (layer*4096+code)
  const int layer = R >> 12, c = R & 4095;
  const int t = tid & 31;
  const float4 v0 = *(const float4*)&cbs[(size_t)R * DIMD + t * 8];
  const float4 v1 = *(const float4*)&cbs[(size_t)R * DIMD + t * 8 + 4];
  const float f[8] = {v0.x, v0.y, v0.z, v0.w, v1.x, v1.y, v1.z, v1.w};
  ushort8 h, l;
  float s = 0.f;
  #pragma unroll
  for (int j = 0; j < 8; ++j) {
    const unsigned short hb = f2bf(f[j]);
    h[j] = hb;
    l[j] = f2bf(f[j] - bf2f(hb));
    s += f[j] * f[j];
  }
  const int kc = t >> 2, qd = t & 3;
  unsigned short* BhL = Bh + (size_t)layer * KCB * DIMD;
  unsigned short* BlL = Bl + (size_t)layer * KCB * DIMD;
  const size_t slot = ((size_t)(kc * KCB + c)) * 4 + (qd ^ ((c >> 1) & 3));
  *(ushort8*)&BhL[slot * 8] = h;
  *(ushort8*)&BlL[slot * 8] = l;
  #pragma unroll
  for (int off = 16; off > 0; off >>= 1) s += __shfl_down(s, off, 32);
  if (t == 0) cn[R] = s;
}

// ---------------------------------------------------------------- argmin (MFMA)
__global__ __launch_bounds__(256, 2) void argmin_kernel(
    const unsigned short* __restrict__ Ah_g,
    const unsigned short* __restrict__ Al_g,
    const unsigned short* __restrict__ Bh_g,
    const unsigned short* __restrict__ Bl_g,
    const float* __restrict__ cn,
    float4* __restrict__ part)        // [NTOK][32] (v1, i1, v2, i2)
{
  __shared__ unsigned short Ah_s[BM * BK];
  __shared__ unsigned short Al_s[BM * BK];
  __shared__ unsigned short Bh_s[BN * BK];
  __shared__ unsigned short Bl_s[BN * BK];
  __shared__ float cnS[BN];

  const int tid  = threadIdx.x;
  const int lane = tid & 63, w = tid >> 6;
  const int colTile = blockIdx.x;       // 0..31
  const int rowBase = blockIdx.y * BM;  // 0..255 tiles
  const int colBase = colTile * BN;

  if (tid < BN) cnS[tid] = cn[colBase + tid];

  f32x4 acc[2][8];
  #pragma unroll
  for (int i = 0; i < 2; ++i)
    #pragma unroll
    for (int j = 0; j < 8; ++j) acc[i][j] = (f32x4){0.f, 0.f, 0.f, 0.f};

  const int quad = lane >> 4, ln = lane & 15;

  for (int kc = 0; kc < DIMD / BK; ++kc) {
    __syncthreads();
    #pragma unroll
    for (int s = 0; s < 2; ++s) {
      const int ch = w * 2 + s;  // 0..7, 16 rows each
      const size_t aoff = ((size_t)(kc * NTOK + rowBase + ch * 16)) * 64 + (size_t)lane * 16;
      const size_t boff = ((size_t)(kc * KCB  + colBase + ch * 16)) * 64 + (size_t)lane * 16;
      async16((const char*)Ah_g + aoff, (char*)Ah_s + ch * 1024);
      async16((const char*)Al_g + aoff, (char*)Al_s + ch * 1024);
      async16((const char*)Bh_g + boff, (char*)Bh_s + ch * 1024);
      async16((const char*)Bl_g + boff, (char*)Bl_s + ch * 1024);
    }
    __syncthreads();

    short8 ah[2], al[2];
    #pragma unroll
    for (int i = 0; i < 2; ++i) {
      const int r = w * 32 + i * 16 + ln;
      const int sl = r * 4 + (quad ^ ((r >> 1) & 3));
      ah[i] = *(const short8*)&Ah_s[sl * 8];
      al[i] = *(const short8*)&Al_s[sl * 8];
    }
    #pragma unroll
    for (int j = 0; j < 8; ++j) {
      const int c = j * 16 + ln;
      const int sl = c * 4 + (quad ^ ((c >> 1) & 3));
      const short8 bh = *(const short8*)&Bh_s[sl * 8];
      const short8 bl = *(const short8*)&Bl_s[sl * 8];
      acc[0][j] = mfma16(ah[0], bh, acc[0][j]);
      acc[1][j] = mfma16(ah[1], bh, acc[1][j]);
      acc[0][j] = mfma16(al[0], bh, acc[0][j]);
      acc[1][j] = mfma16(al[1], bh, acc[1][j]);
      acc[0][j] = mfma16(ah[0], bl, acc[0][j]);
      acc[1][j] = mfma16(ah[1], bl, acc[1][j]);
    }
  }

  // epilogue: dist = cn - 2*dot (rn constant per row — argmin-equivalent)
  #pragma unroll
  for (int i = 0; i < 2; ++i) {
    #pragma unroll
    for (int reg = 0; reg < 4; ++reg) {
      float v1 = 3.0e38f, v2 = 3.0e38f; int i1 = 0, i2 = 1;
      #pragma unroll
      for (int j = 0; j < 8; ++j) {
        const float d = cnS[j * 16 + ln] - 2.0f * acc[i][j][reg];
        merge1(v1, i1, v2, i2, d, colBase + j * 16 + ln);
      }
      #pragma unroll
      for (int m = 1; m <= 8; m <<= 1) {
        const float u1 = __shfl_xor(v1, m, 64);
        const int   j1 = __shfl_xor(i1, m, 64);
        const float u2 = __shfl_xor(v2, m, 64);
        const int   j2 = __shfl_xor(i2, m, 64);
        merge2(v1, i1, v2, i2, u1, j1, u2, j2);
      }
      if (ln == 0) {
        const int rowg = rowBase + w * 32 + i * 16 + quad * 4 + reg;
        part[(size_t)rowg * 32 + colTile] =
            make_float4(v1, __int_as_float(i1), v2, __int_as_float(i2));
      }
    }
  }
}

// ---------------------------------------------------------------- merge partials
__global__ void merge_kernel(const float4* __restrict__ part,
                             int2* __restrict__ cand) {
  const int row = blockIdx.x * 256 + threadIdx.x;
  float v1 = 3.0e38f, v2 = 3.0e38f; int i1 = 0, i2 = 1;
  for (int t = 0; t < 32; ++t) {
    const float4 p = part[(size_t)row * 32 + t];
    merge2(v1, i1, v2, i2, p.x, __float_as_int(p.y), p.z, __float_as_int(p.w));
  }
  cand[row] = make_int2(i1, i2);
}

// ---------------------------------------------------------------- fp64 rescore
__global__ void rescore_kernel(const float* __restrict__ res,
                               const float* __restrict__ cb,
                               const int2* __restrict__ cand,
                               int* __restrict__ idx,
                               float* __restrict__ idxf) {
  const int lane = threadIdx.x & 63;
  const int rsub = threadIdx.x >> 6;
  const int n = blockIdx.x * 4 + rsub;
  const int2 c = cand[n];
  const float* rrow = res + (size_t)n * DIMD;
  const float* c1 = cb + (size_t)c.x * DIMD;
  const float* c2 = cb + (size_t)c.y * DIMD;
  double d1 = 0.0, d2 = 0.0;
  #pragma unroll
  for (int j = 0; j < 4; ++j) {
    const int d = j * 64 + lane;
    const double rv = (double)rrow[d];
    const double t1 = rv - (double)c1[d];
    const double t2 = rv - (double)c2[d];
    d1 += t1 * t1; d2 += t2 * t2;
  }
  #pragma unroll
  for (int off = 32; off > 0; off >>= 1) {
    d1 += __shfl_down(d1, off, 64);
    d2 += __shfl_down(d2, off, 64);
  }
  if (lane == 0) {
    const int best = (d2 < d1 || (d2 == d1 && c.y < c.x)) ? c.y : c.x;
    idx[n]  = best;
    idxf[n] = (float)best;
  }
}

// ---------------------------------------------------------------- STE update
__global__ void update_kernel(float* __restrict__ res,
                              const float* __restrict__ cb,
                              const int* __restrict__ idx,
                              float* __restrict__ out,
                              unsigned short* __restrict__ Ah,
                              unsigned short* __restrict__ Al,
                              float* __restrict__ loss,
                              int emit) {
  __shared__ float sbuf[4];
  const int tid = threadIdx.x;
  const int n = blockIdx.x * 8 + (tid >> 5);
  const int t = tid & 31;
  const int i = idx[n];
  const size_t base = (size_t)n * DIMD + t * 8;
  const float4 r0 = *(const float4*)&res[base];
  const float4 r1 = *(const float4*)&res[base + 4];
  const float4 q0 = *(const float4*)&cb[(size_t)i * DIMD + t * 8];
  const float4 q1 = *(const float4*)&cb[(size_t)i * DIMD + t * 8 + 4];
  const float rr[8] = {r0.x, r0.y, r0.z, r0.w, r1.x, r1.y, r1.z, r1.w};
  const float qq[8] = {q0.x, q0.y, q0.z, q0.w, q1.x, q1.y, q1.z, q1.w};
  float nr[8], st[8];
  float s2 = 0.f;
  #pragma unroll
  for (int j = 0; j < 8; ++j) {
    const float stv = rr[j] + (qq[j] - rr[j]);   // STE value, ref rounding
    st[j] = stv;
    nr[j] = rr[j] - stv;
    const float dl = rr[j] - qq[j];
    s2 += dl * dl;
  }
  *(float4*)&res[base]     = make_float4(nr[0], nr[1], nr[2], nr[3]);
  *(float4*)&res[base + 4] = make_float4(nr[4], nr[5], nr[6], nr[7]);
  float4 o0 = *(const float4*)&out[base];
  float4 o1 = *(const float4*)&out[base + 4];
  o0.x += st[0]; o0.y += st[1]; o0.z += st[2]; o0.w += st[3];
  o1.x += st[4]; o1.y += st[5]; o1.z += st[6]; o1.w += st[7];
  *(float4*)&out[base]     = o0;
  *(float4*)&out[base + 4] = o1;
  if (emit) {
    ushort8 h, l;
    #pragma unroll
    for (int j = 0; j < 8; ++j) {
      const unsigned short hb = f2bf(nr[j]);
      h[j] = hb;
      l[j] = f2bf(nr[j] - bf2f(hb));
    }
    const int kc = t >> 2, qd = t & 3;
    const size_t slot = ((size_t)(kc * NTOK + n)) * 4 + (qd ^ ((n >> 1) & 3));
    *(ushort8*)&Ah[slot * 8] = h;
    *(ushort8*)&Al[slot * 8] = l;
  }
  #pragma unroll
  for (int off = 32; off > 0; off >>= 1) s2 += __shfl_down(s2, off, 64);
  const int lane = tid & 63, wid = tid >> 6;
  if (lane == 0) sbuf[wid] = s2;
  __syncthreads();
  if (tid == 0) {
    const float tot = sbuf[0] + sbuf[1] + sbuf[2] + sbuf[3];
    atomicAdd(loss, tot * (1.0f / (float)((size_t)NTOK * DIMD)));
  }
}

// ---------------------------------------------------------------- launch
extern "C" void kernel_launch(void* const* d_in, const int* in_sizes, int n_in,
                              void* d_out, int out_size, void* d_ws, size_t ws_size,
                              hipStream_t stream) {
  const float* x   = (const float*)d_in[0];   // [8,4096,256]
  const float* cbs = (const float*)d_in[1];   // [4,4096,256]

  float* out    = (float*)d_out;
  float* idxf   = out + (size_t)NTOK * DIMD;
  float* losses = idxf + (size_t)NQ * NTOK;

  char* wsp = (char*)d_ws;
  float* res = (float*)wsp;           wsp += (size_t)NTOK * DIMD * 4;       // 32 MB
  unsigned short* Ah = (unsigned short*)wsp; wsp += (size_t)NTOK * DIMD * 2; // 16 MB
  unsigned short* Al = (unsigned short*)wsp; wsp += (size_t)NTOK * DIMD * 2; // 16 MB
  unsigned short* Bh = (unsigned short*)wsp; wsp += (size_t)NQ * KCB * DIMD * 2; // 8 MB
  unsigned short* Bl = (unsigned short*)wsp; wsp += (size_t)NQ * KCB * DIMD * 2; // 8 MB
  float4* part = (float4*)wsp;        wsp += (size_t)NTOK * 32 * 16;        // 16 MB
  float* cn = (float*)wsp;            wsp += (size_t)NQ * KCB * 4;
  int2* cand = (int2*)wsp;            wsp += (size_t)NTOK * 8;
  int* idx = (int*)wsp;               wsp += (size_t)NTOK * 4;

  hipMemsetAsync(d_out, 0, (size_t)out_size * sizeof(float), stream);
  cb_prep_kernel<<<NQ * KCB / 8, 256, 0, stream>>>(cbs, Bh, Bl, cn);
  init_kernel<<<NTOK / 8, 256, 0, stream>>>(x, res, Ah, Al);

  for (int q = 0; q < NQ; ++q) {
    const float* cb = cbs + (size_t)q * KCB * DIMD;
    argmin_kernel<<<dim3(KCB / BN, NTOK / BM), 256, 0, stream>>>(
        Ah, Al,
        Bh + (size_t)q * KCB * DIMD, Bl + (size_t)q * KCB * DIMD,
        cn + (size_t)q * KCB, part);
    merge_kernel<<<NTOK / 256, 256, 0, stream>>>(part, cand);
    rescore_kernel<<<NTOK / 4, 256, 0, stream>>>(res, cb, cand, idx, idxf + (size_t)q * NTOK);
    update_kernel<<<NTOK / 8, 256, 0, stream>>>(res, cb, idx, out, Ah, Al,
                                                losses + q, q < NQ - 1 ? 1 : 0);
  }
}

// Round 3
// 1551.113 us; speedup vs baseline: 4.2839x; 2.2979x over previous
//
#include <hip/hip_runtime.h>
#include <cstdint>

#define DIMD 256
#define KCB  4096
#define NQ   4
#define NTOK 32768   // 8 * 4096
#define BN   128     // cols per block (persistent B in LDS)
#define RPB  4096    // rows per block (NTOK / 8 row groups)
#define RT   512     // rows per iteration (8 waves x 64)

typedef __attribute__((ext_vector_type(8))) _Float16 half8;
typedef __attribute__((ext_vector_type(4))) float f32x4;

// ---------------------------------------------------------------- helpers
__device__ __forceinline__ void async16(const void* g, void* l) {
  __builtin_amdgcn_global_load_lds(
      (const __attribute__((address_space(1))) unsigned int*)g,
      (__attribute__((address_space(3))) unsigned int*)l, 16, 0, 0);
}

__device__ __forceinline__ f32x4 mfma16(half8 a, half8 b, f32x4 c) {
  return __builtin_amdgcn_mfma_f32_16x16x32_f16(a, b, c, 0, 0, 0);
}

// ---------------------------------------------------------------- prep
// A plane pre-tiled frag-linear for mfma_f32_16x16x32 A-operand:
// half index = ((kc*(NTOK/16) + rowBlock16)*64 + (q*16 + (row&15)))*8 + j
// where element (row, d): kc=d>>5, q=(d>>3)&3, j=d&7.
__global__ void init_kernel(const float* __restrict__ x,
                            float* __restrict__ res,
                            _Float16* __restrict__ At) {
  const int tid = threadIdx.x;
  const int n = blockIdx.x * 8 + (tid >> 5);
  const int t = tid & 31;
  const size_t base = (size_t)n * DIMD + t * 8;
  const float4 v0 = *(const float4*)&x[base];
  const float4 v1 = *(const float4*)&x[base + 4];
  *(float4*)&res[base]     = v0;
  *(float4*)&res[base + 4] = v1;
  const float f[8] = {v0.x, v0.y, v0.z, v0.w, v1.x, v1.y, v1.z, v1.w};
  half8 h;
  #pragma unroll
  for (int j = 0; j < 8; ++j) h[j] = (_Float16)f[j];
  const int kc = t >> 2, q = t & 3;
  *(half8*)&At[(((size_t)(kc * (NTOK / 16) + (n >> 4))) * 64 + q * 16 + (n & 15)) * 8] = h;
}

__global__ void cb_prep_kernel(const float* __restrict__ cbs,
                               _Float16* __restrict__ Bt,
                               float* __restrict__ cn) {
  const int tid = threadIdx.x;
  const int R = blockIdx.x * 8 + (tid >> 5);   // layer*4096 + code
  const int layer = R >> 12, c = R & 4095;
  const int t = tid & 31;
  const size_t base = (size_t)R * DIMD + t * 8;
  const float4 v0 = *(const float4*)&cbs[base];
  const float4 v1 = *(const float4*)&cbs[base + 4];
  const float f[8] = {v0.x, v0.y, v0.z, v0.w, v1.x, v1.y, v1.z, v1.w};
  half8 h;
  float s = 0.f;
  #pragma unroll
  for (int j = 0; j < 8; ++j) { h[j] = (_Float16)f[j]; s += f[j] * f[j]; }
  const int kc = t >> 2, q = t & 3;
  _Float16* BtL = Bt + (size_t)layer * KCB * DIMD;
  *(half8*)&BtL[(((size_t)(kc * (KCB / 16) + (c >> 4))) * 64 + q * 16 + (c & 15)) * 8] = h;
  #pragma unroll
  for (int off = 16; off > 0; off >>= 1) s += __shfl_down(s, off, 32);
  if (t == 0) cn[R] = s;
}

// ---------------------------------------------------------------- argmin
// Persistent B (128 cols x 256 dims fp16 = 64 KB LDS), A direct global->VGPR,
// no barriers in the main loop. 8 waves; wave tile 64 rows x 128 cols.
__global__ __launch_bounds__(512, 2) void argmin_kernel(
    const _Float16* __restrict__ At,
    const _Float16* __restrict__ Bt,     // layer base
    const float* __restrict__ cn,        // layer base
    float4* __restrict__ part)           // [NTOK][32] (v1,i1,v2,i2)
{
  __shared__ _Float16 Bs[BN * DIMD];     // frag id = kc*8+f at id*512 halfs

  const int tid = threadIdx.x;
  const int lane = tid & 63, w = tid >> 6;
  const int colTile = blockIdx.x & 31;
  const int g = blockIdx.x >> 5;         // row group 0..7
  const int colBase = colTile * BN;
  const int quad = lane >> 4, ln = lane & 15;

  // stage B once (8 x 1KB fragments per wave)
  #pragma unroll
  for (int s = 0; s < 8; ++s) {
    const int id = w * 8 + s;            // kc = id>>3, f = id&7
    const int kc = id >> 3, f = id & 7;
    const size_t goff = (((size_t)(kc * (KCB / 16) + colTile * 8 + f)) * 64 + lane) * 16;
    async16((const char*)Bt + goff, (char*)Bs + (size_t)id * 1024);
  }
  float cnv[8];
  #pragma unroll
  for (int j = 0; j < 8; ++j) cnv[j] = cn[colBase + j * 16 + ln];
  __syncthreads();   // the only barrier

  int rb = g * (RPB / 16) + w * 4;       // rowBlock16 base at rt=0
  half8 a_cur[4];
  #pragma unroll
  for (int i = 0; i < 4; ++i)
    a_cur[i] = *(const half8*)&At[(((size_t)(rb + i)) * 64 + lane) * 8];  // kc=0

  for (int rt = 0; rt < RPB / RT; ++rt) {
    f32x4 acc[4][8];
    #pragma unroll
    for (int i = 0; i < 4; ++i)
      #pragma unroll
      for (int j = 0; j < 8; ++j) acc[i][j] = (f32x4){0.f, 0.f, 0.f, 0.f};

    #pragma unroll
    for (int kc = 0; kc < 8; ++kc) {
      // prefetch next (kc+1, or next rt kc=0; wraps harmlessly on last)
      int nkc = kc + 1, nrb = rb;
      if (nkc == 8) { nkc = 0; nrb = (rt == RPB / RT - 1) ? g * (RPB / 16) + w * 4 : rb + 32; }
      half8 a_nxt[4];
      #pragma unroll
      for (int i = 0; i < 4; ++i)
        a_nxt[i] = *(const half8*)&At[(((size_t)(nkc * (NTOK / 16) + nrb + i)) * 64 + lane) * 8];

      #pragma unroll
      for (int j = 0; j < 8; ++j) {
        const half8 b = *(const half8*)&Bs[((size_t)(kc * 8 + j)) * 512 + lane * 8];
        acc[0][j] = mfma16(a_cur[0], b, acc[0][j]);
        acc[1][j] = mfma16(a_cur[1], b, acc[1][j]);
        acc[2][j] = mfma16(a_cur[2], b, acc[2][j]);
        acc[3][j] = mfma16(a_cur[3], b, acc[3][j]);
      }
      #pragma unroll
      for (int i = 0; i < 4; ++i) a_cur[i] = a_nxt[i];
    }

    // epilogue: best-2 per row over this block's 128 cols (no tie-break
    // needed — global top-8 fp64 rescore is the arbiter)
    #pragma unroll
    for (int i = 0; i < 4; ++i) {
      #pragma unroll
      for (int reg = 0; reg < 4; ++reg) {
        float v1 = 3.0e38f, v2 = 3.0e38f; int i1 = colBase, i2 = colBase + 1;
        #pragma unroll
        for (int j = 0; j < 8; ++j) {
          const float d = cnv[j] - 2.0f * acc[i][j][reg];
          const int c = colBase + j * 16 + ln;
          if (d < v1) { v2 = v1; i2 = i1; v1 = d; i1 = c; }
          else if (d < v2) { v2 = d; i2 = c; }
        }
        #pragma unroll
        for (int m = 1; m <= 8; m <<= 1) {
          const float u1 = __shfl_xor(v1, m, 64); const int j1 = __shfl_xor(i1, m, 64);
          const float u2 = __shfl_xor(v2, m, 64); const int j2 = __shfl_xor(i2, m, 64);
          if (u1 < v1) {
            v2 = (u2 < v1) ? u2 : v1; i2 = (u2 < v1) ? j2 : i1;
            v1 = u1; i1 = j1;
          } else if (u1 < v2) { v2 = u1; i2 = j1; }
        }
        if (ln == 0) {
          const int rowg = g * RPB + rt * RT + w * 64 + i * 16 + quad * 4 + reg;
          part[(size_t)rowg * 32 + colTile] =
              make_float4(v1, __int_as_float(i1), v2, __int_as_float(i2));
        }
      }
    }
    rb += 32;
  }
}

// ---------------------------------------------------------------- top-8 + fp64 rescore
__global__ void rescore_kernel(const float* __restrict__ res,
                               const float* __restrict__ cb,
                               const float4* __restrict__ part,
                               int* __restrict__ idx,
                               float* __restrict__ idxf) {
  const int lane = threadIdx.x & 63;
  const int row = blockIdx.x * 4 + (threadIdx.x >> 6);
  const float4 p = part[(size_t)row * 32 + (lane >> 1)];
  float v = (lane & 1) ? p.z : p.x;
  int   c = __float_as_int((lane & 1) ? p.w : p.y);
  const float4 r4 = *(const float4*)&res[(size_t)row * DIMD + lane * 4];

  int cand8[8];
  #pragma unroll
  for (int it = 0; it < 8; ++it) {
    float bv = v; int bi = c;
    #pragma unroll
    for (int m = 1; m < 64; m <<= 1) {
      const float ov = __shfl_xor(bv, m, 64);
      const int   oi = __shfl_xor(bi, m, 64);
      if (ov < bv || (ov == bv && oi < bi)) { bv = ov; bi = oi; }
    }
    cand8[it] = bi;
    if (c == bi) v = 3.0e38f;   // candidates are globally unique by col
  }

  double best = 1.0e300; int besti = KCB;
  #pragma unroll
  for (int it = 0; it < 8; ++it) {
    const int cc = cand8[it];
    const float4 q4 = *(const float4*)&cb[(size_t)cc * DIMD + lane * 4];
    const double t0 = (double)r4.x - (double)q4.x;
    const double t1 = (double)r4.y - (double)q4.y;
    const double t2 = (double)r4.z - (double)q4.z;
    const double t3 = (double)r4.w - (double)q4.w;
    double d = t0 * t0 + t1 * t1 + t2 * t2 + t3 * t3;
    #pragma unroll
    for (int m = 1; m < 64; m <<= 1) d += __shfl_xor(d, m, 64);
    if (d < best || (d == best && cc < besti)) { best = d; besti = cc; }
  }
  if (lane == 0) { idx[row] = besti; idxf[row] = (float)besti; }
}

// ---------------------------------------------------------------- STE update
__global__ void update_kernel(float* __restrict__ res,
                              const float* __restrict__ cb,
                              const int* __restrict__ idx,
                              float* __restrict__ out,
                              _Float16* __restrict__ At,
                              float* __restrict__ loss,
                              int emit) {
  __shared__ float sbuf[4];
  const int tid = threadIdx.x;
  const int n = blockIdx.x * 8 + (tid >> 5);
  const int t = tid & 31;
  const int i = idx[n];
  const size_t base = (size_t)n * DIMD + t * 8;
  const float4 r0 = *(const float4*)&res[base];
  const float4 r1 = *(const float4*)&res[base + 4];
  const float4 q0 = *(const float4*)&cb[(size_t)i * DIMD + t * 8];
  const float4 q1 = *(const float4*)&cb[(size_t)i * DIMD + t * 8 + 4];
  const float rr[8] = {r0.x, r0.y, r0.z, r0.w, r1.x, r1.y, r1.z, r1.w};
  const float qq[8] = {q0.x, q0.y, q0.z, q0.w, q1.x, q1.y, q1.z, q1.w};
  float nr[8], st[8];
  float s2 = 0.f;
  #pragma unroll
  for (int j = 0; j < 8; ++j) {
    const float stv = rr[j] + (qq[j] - rr[j]);   // STE value, ref rounding
    st[j] = stv;
    nr[j] = rr[j] - stv;
    const float dl = rr[j] - qq[j];
    s2 += dl * dl;
  }
  *(float4*)&res[base]     = make_float4(nr[0], nr[1], nr[2], nr[3]);
  *(float4*)&res[base + 4] = make_float4(nr[4], nr[5], nr[6], nr[7]);
  float4 o0 = *(const float4*)&out[base];
  float4 o1 = *(const float4*)&out[base + 4];
  o0.x += st[0]; o0.y += st[1]; o0.z += st[2]; o0.w += st[3];
  o1.x += st[4]; o1.y += st[5]; o1.z += st[6]; o1.w += st[7];
  *(float4*)&out[base]     = o0;
  *(float4*)&out[base + 4] = o1;
  if (emit) {
    half8 h;
    #pragma unroll
    for (int j = 0; j < 8; ++j) h[j] = (_Float16)nr[j];
    const int kc = t >> 2, q = t & 3;
    *(half8*)&At[(((size_t)(kc * (NTOK / 16) + (n >> 4))) * 64 + q * 16 + (n & 15)) * 8] = h;
  }
  #pragma unroll
  for (int off = 32; off > 0; off >>= 1) s2 += __shfl_down(s2, off, 64);
  const int lane = tid & 63, wid = tid >> 6;
  if (lane == 0) sbuf[wid] = s2;
  __syncthreads();
  if (tid == 0) {
    const float tot = sbuf[0] + sbuf[1] + sbuf[2] + sbuf[3];
    atomicAdd(loss, tot * (1.0f / (float)((size_t)NTOK * DIMD)));
  }
}

// ---------------------------------------------------------------- launch
extern "C" void kernel_launch(void* const* d_in, const int* in_sizes, int n_in,
                              void* d_out, int out_size, void* d_ws, size_t ws_size,
                              hipStream_t stream) {
  const float* x   = (const float*)d_in[0];   // [8,4096,256]
  const float* cbs = (const float*)d_in[1];   // [4,4096,256]

  float* out    = (float*)d_out;
  float* idxf   = out + (size_t)NTOK * DIMD;
  float* losses = idxf + (size_t)NQ * NTOK;

  char* wsp = (char*)d_ws;
  float* res = (float*)wsp;                    wsp += (size_t)NTOK * DIMD * 4;      // 32 MB
  _Float16* At = (_Float16*)wsp;               wsp += (size_t)NTOK * DIMD * 2;      // 16 MB
  _Float16* Bt = (_Float16*)wsp;               wsp += (size_t)NQ * KCB * DIMD * 2;  //  8 MB
  float4* part = (float4*)wsp;                 wsp += (size_t)NTOK * 32 * 16;       // 16 MB
  float* cn = (float*)wsp;                     wsp += (size_t)NQ * KCB * 4;
  int* idx = (int*)wsp;                        wsp += (size_t)NTOK * 4;

  hipMemsetAsync(d_out, 0, (size_t)out_size * sizeof(float), stream);
  cb_prep_kernel<<<NQ * KCB / 8, 256, 0, stream>>>(cbs, Bt, cn);
  init_kernel<<<NTOK / 8, 256, 0, stream>>>(x, res, At);

  for (int q = 0; q < NQ; ++q) {
    const float* cb = cbs + (size_t)q * KCB * DIMD;
    argmin_kernel<<<256, 512, 0, stream>>>(At, Bt + (size_t)q * KCB * DIMD,
                                           cn + (size_t)q * KCB, part);
    rescore_kernel<<<NTOK / 4, 256, 0, stream>>>(res, cb, part, idx,
                                                 idxf + (size_t)q * NTOK);
    update_kernel<<<NTOK / 8, 256, 0, stream>>>(res, cb, idx, out, At,
                                                losses + q, q < NQ - 1 ? 1 : 0);
  }
}